// Round 1
// baseline (218.853 us; speedup 1.0000x reference)
//
#include <hip/hip_runtime.h>
#include <stdint.h>

#define D_DIM 784
#define H_DIM 1024
#define B_DIM 256
#define NBIN  10
#define G_CH  8             // chunk length (i's per main block)
#define T_CH  98            // D_DIM / G_CH
#define BT    16            // batch tile per main block (fixed by MFMA M=16)
#define BF    2             // batch rows per pscan block
#define LOG2E 1.4426950408889634f

#define PSCAN_BLKS 512      // (B_DIM/BF) * (H_DIM/256)
#define VPREP_BLKS D_DIM    // 784
#define WPREP_BLKS 208      // 13 * 16 tiles of W transpose

typedef _Float16 half8_t  __attribute__((ext_vector_type(8)));
typedef __fp16   fp16x2_t __attribute__((ext_vector_type(2)));
typedef float    float4_t __attribute__((ext_vector_type(4)));

// ---------------------------------------------------------------------------
// k_prep2: ONE dispatch, three independent jobs (no inter-block deps):
//   blocks [0,512)        : prefix-scan PA from W (f32) + x + c   (longest: first)
//   blocks [512,1296)     : V -> VB MFMA-fragment reshape (f16)
//   blocks [1296,1504)    : W -> Wt2h f16 transpose (x LOG2E) for k_main's wlds
// ---------------------------------------------------------------------------
__global__ void k_prep2(const float* __restrict__ W, const float* __restrict__ V,
                        const float* __restrict__ c, const int* __restrict__ x,
                        _Float16* __restrict__ Wt2h, _Float16* __restrict__ VB,
                        _Float16* __restrict__ PA) {
    __shared__ __align__(16) float smem[H_DIM * NBIN];   // 40 KB, aliased by all branches
    int tid = threadIdx.x;
    int bx  = blockIdx.x;

    if (bx < PSCAN_BLKS) {
        // ---- fused partial-sum + exclusive scan, f32 accum, distance-2 prefetch ----
        int q  = bx;
        int b0 = (q & 127) * BF;
        int h  = (q >> 7) * 256 + tid;
        float* xs0 = smem;            // [784]
        float* xs1 = smem + D_DIM;    // [784]
        for (int qq = tid; qq < BF * (D_DIM / 4); qq += 256) {
            int bb = qq / (D_DIM / 4), r = qq % (D_DIM / 4);
            int4 xi = ((const int4*)(x + (size_t)(b0 + bb) * D_DIM))[r];
            float4 xf = make_float4((float)xi.x, (float)xi.y, (float)xi.z, (float)xi.w);
            *((float4*)((bb ? xs1 : xs0) + r * 4)) = xf;
        }
        float acc0 = c[h], acc1 = acc0;        // natural domain; scale at store
        __syncthreads();
        const float4* w4 = (const float4*)(W + (size_t)h * D_DIM);  // per-thread contiguous row
        _Float16* pa = PA + (size_t)b0 * H_DIM + h;

        auto pstore = [&](int t_) {
            pa[(size_t)t_ * (B_DIM * H_DIM)]         = (_Float16)(acc0 * LOG2E);
            pa[(size_t)t_ * (B_DIM * H_DIM) + H_DIM] = (_Float16)(acc1 * LOG2E);
        };
        auto pfma = [&](float4 w0_, float4 w1_, int t_) {
            float4 xa0 = *((const float4*)(xs0 + t_ * 8));
            float4 xa1 = *((const float4*)(xs0 + t_ * 8 + 4));
            float4 xb0 = *((const float4*)(xs1 + t_ * 8));
            float4 xb1 = *((const float4*)(xs1 + t_ * 8 + 4));
            acc0 += xa0.x*w0_.x + xa0.y*w0_.y + xa0.z*w0_.z + xa0.w*w0_.w
                  + xa1.x*w1_.x + xa1.y*w1_.y + xa1.z*w1_.z + xa1.w*w1_.w;
            acc1 += xb0.x*w0_.x + xb0.y*w0_.y + xb0.z*w0_.z + xb0.w*w0_.w
                  + xb1.x*w1_.x + xb1.y*w1_.y + xb1.z*w1_.z + xb1.w*w1_.w;
        };

        float4 wA0 = w4[0], wA1 = w4[1], wB0 = w4[2], wB1 = w4[3];
        for (int t = 0; t < T_CH - 2; t += 2) {
            // issue next loads BEFORE stores so waitcnt on w-use never drains the stores
            float4 nA0 = w4[(t + 2) * 2], nA1 = w4[(t + 2) * 2 + 1];
            float4 nB0 = w4[(t + 3) * 2], nB1 = w4[(t + 3) * 2 + 1];
            pstore(t);     pfma(wA0, wA1, t);
            pstore(t + 1); pfma(wB0, wB1, t + 1);
            wA0 = nA0; wA1 = nA1; wB0 = nB0; wB1 = nB1;
        }
        pstore(96); pfma(wA0, wA1, 96);
        pstore(97);                      // final chunk's update is never consumed
    } else if (bx < PSCAN_BLKS + VPREP_BLKS) {
        // ---- V -> VB fragment reshape ----
        int i = bx - PSCAN_BLKS;
        const float4* src = (const float4*)(V + (size_t)i * H_DIM * NBIN);
        #pragma unroll
        for (int qv = 0; qv < 10; ++qv) {
            float4 v = src[qv * 256 + tid];
            *((float4*)&smem[(qv * 256 + tid) * 4]) = v;
        }
        __syncthreads();
        #pragma unroll
        for (int qv = 0; qv < 8; ++qv) {
            int pair = qv * 256 + tid;          // (kk,l) pair 0..2047
            int kk = pair >> 6, ll = pair & 63;
            int n = ll & 15, hb = kk * 32 + ((ll >> 4) & 3) * 8;
            union { _Float16 hh[8]; uint4 u; } o;
            #pragma unroll
            for (int jj = 0; jj < 8; ++jj)
                o.hh[jj] = (_Float16)((n < NBIN) ? smem[(hb + jj) * NBIN + n] : 0.0f);
            ((uint4*)VB)[(size_t)i * 2048 + pair] = o.u;
        }
    } else {
        // ---- W transpose -> Wt2h (f16, x LOG2E) ----
        int qw = bx - PSCAN_BLKS - VPREP_BLKS;  // 0..207
        int j0 = (qw % 13) * 64, h0 = (qw / 13) * 64;
        float (*t)[65] = (float(*)[65])smem;    // 16.6 KB view
        int tj = tid & 63, tr = tid >> 6;
        int j = j0 + tj;
        #pragma unroll
        for (int r = 0; r < 16; ++r) {
            int hh = tr * 16 + r;
            t[hh][tj] = (j < D_DIM) ? W[(size_t)(h0 + hh) * D_DIM + j] : 0.0f;
        }
        __syncthreads();
        #pragma unroll
        for (int r = 0; r < 16; ++r) {
            int jj = tr * 16 + r;
            int jo = j0 + jj;
            if (jo < D_DIM) Wt2h[(size_t)jo * H_DIM + h0 + tj] = (_Float16)(t[tj][jj] * LOG2E);
        }
    }
}

// ---------------------------------------------------------------------------
// main fused kernel: rolling 3-slot VB prefetch, streamed cf flush (low VGPR),
// launch_bounds(256,4) -> 4 blocks/CU (LDS 35.3 KB x 4 = 141 KB fits).
// ---------------------------------------------------------------------------
__global__ __launch_bounds__(256, 4)
void k_main(const _Float16* __restrict__ VB, const _Float16* __restrict__ Wt2h,
            const _Float16* __restrict__ PA, const int* __restrict__ x,
            const float* __restrict__ bias, float* __restrict__ out) {
    int bt  = blockIdx.x;        // batch tile 0..15 (fast dim: VB L2 reuse)
    int tc  = blockIdx.y;        // chunk 0..97
    int tid = threadIdx.x;
    int w   = tid >> 6;          // wave 0..3 (K-split of H)
    int l   = tid & 63;
    int bl  = l & 15;            // MFMA A row == batch row within tile
    int kg  = l >> 4;            // 0..3
    int bg  = bt * BT + bl;
    int i0  = tc * G_CH;

    __shared__ __align__(16) _Float16 wlds[G_CH][H_DIM]; // 16 KB
    __shared__ float red[4][64][18];                     // 18.4 KB, stride-18: 2-way max (free)
    __shared__ float bs[G_CH][16];                       // 0.5 KB

    {   // stage bias chunk
        int ii = tid >> 4, n = tid & 15;
        if (ii < G_CH) bs[ii][n] = (n < NBIN) ? bias[(size_t)(i0 + ii) * NBIN + n] : 0.0f;
    }
    {   // stage Wt2h chunk rows i0..i0+7 (f16 direct copy, coalesced)
        #pragma unroll
        for (int r = 0; r < G_CH; ++r) {
            uint2 v = ((const uint2*)(Wt2h + (size_t)(i0 + r) * H_DIM))[tid];
            *((uint2*)&wlds[r][tid * 4]) = v;
        }
    }
    float xvf[G_CH];
    {
        const int4* xp = (const int4*)(x + (size_t)bg * D_DIM + i0);
        int4 x0 = xp[0], x1 = xp[1];
        xvf[0] = (float)x0.x; xvf[1] = (float)x0.y; xvf[2] = (float)x0.z; xvf[3] = (float)x0.w;
        xvf[4] = (float)x1.x; xvf[5] = (float)x1.y; xvf[6] = (float)x1.z; xvf[7] = (float)x1.w;
    }
    float a[8][8];
    {
        const _Float16* src = PA + ((size_t)tc * B_DIM + bg) * H_DIM + w * 256 + kg * 8;
        #pragma unroll
        for (int m = 0; m < 8; ++m) {
            half8_t av = *((const half8_t*)(src + m * 32));
            #pragma unroll
            for (int j = 0; j < 8; ++j) a[m][j] = (float)av[j];
        }
    }

    // rolling 3-slot VB prefetch: slot mm%3 used at step mm, refilled for mm+2
    const uint4* vp = (const uint4*)VB + ((size_t)i0 * 32 + w * 8) * 64 + l;
    uint4 vbuf[3];
    vbuf[0] = vp[0];                 // (ii=0, m=0)
    vbuf[1] = vp[64];                // (ii=0, m=1)
    float4_t acc = {0.f, 0.f, 0.f, 0.f};

    auto step = [&](int mm) {        // mm = ii*8 + m, all indices static after unroll
        const int ii = mm >> 3, m = mm & 7;
        if (mm + 2 < 64) {
            const int nn = mm + 2;
            vbuf[nn % 3] = vp[((nn >> 3) * 32 + (nn & 7)) * 64];
        }
        union { half8_t h8; uint u32[4]; } af;
        #pragma unroll
        for (int p = 0; p < 4; ++p) {
            float s0 = __builtin_amdgcn_rcpf(1.0f + __builtin_amdgcn_exp2f(-a[m][2 * p]));
            float s1 = __builtin_amdgcn_rcpf(1.0f + __builtin_amdgcn_exp2f(-a[m][2 * p + 1]));
            union { fp16x2_t v; uint u; } cv;
            cv.v = __builtin_amdgcn_cvt_pkrtz(s0, s1);
            af.u32[p] = cv.u;
        }
        union { half8_t h8; uint4 u; } bf;
        bf.u = vbuf[mm % 3];
        acc = __builtin_amdgcn_mfma_f32_16x16x32_f16(af.h8, bf.h8, acc, 0, 0, 0);
        half8_t wh = *((const half8_t*)&wlds[ii][w * 256 + kg * 8 + m * 32]);
        float xf = xvf[ii];
        a[m][0] += xf * (float)wh[0]; a[m][1] += xf * (float)wh[1];
        a[m][2] += xf * (float)wh[2]; a[m][3] += xf * (float)wh[3];
        a[m][4] += xf * (float)wh[4]; a[m][5] += xf * (float)wh[5];
        a[m][6] += xf * (float)wh[6]; a[m][7] += xf * (float)wh[7];
        if (m == 7) {                // stream flush: keeps only ONE float4 acc live
            int s = (ii & 3) * 4;
            red[w][l][s + 0] = acc[0]; red[w][l][s + 1] = acc[1];
            red[w][l][s + 2] = acc[2]; red[w][l][s + 3] = acc[3];
            acc = (float4_t){0.f, 0.f, 0.f, 0.f};
        }
    };

    auto softmax_store = [&](int half) {
        float p4[4];
        #pragma unroll
        for (int q = 0; q < 4; ++q) {
            int ii = half * 4 + q;
            float tot = red[0][l][q * 4 + w] + red[1][l][q * 4 + w]
                      + red[2][l][q * 4 + w] + red[3][l][q * 4 + w];
            float v = (bl < NBIN) ? tot + bs[ii][bl] : -3.0e38f;
            float vm = v;
            vm = fmaxf(vm, __shfl_xor(vm, 1));
            vm = fmaxf(vm, __shfl_xor(vm, 2));
            vm = fmaxf(vm, __shfl_xor(vm, 4));
            vm = fmaxf(vm, __shfl_xor(vm, 8));
            float e = __builtin_amdgcn_exp2f((v - vm) * LOG2E);
            float ss = e;
            ss += __shfl_xor(ss, 1); ss += __shfl_xor(ss, 2);
            ss += __shfl_xor(ss, 4); ss += __shfl_xor(ss, 8);
            p4[q] = e * __builtin_amdgcn_rcpf(ss);
        }
        if (bl < NBIN) {
            int b = bt * BT + kg * 4 + w;   // this thread's C row = batch row
            size_t base = ((size_t)b * NBIN + bl) * D_DIM + i0 + half * 4;
            float4 v = make_float4(p4[0], p4[1], p4[2], p4[3]);
            *((float4*)(out + base)) = v;
        }
    };

    __syncthreads();               // B0: wlds/bs staged
    #pragma unroll
    for (int mm = 0; mm < 32; ++mm) step(mm);     // half 0 (red streamed)
    __syncthreads();               // B1: half-0 partials visible
    softmax_store(0);
    __syncthreads();               // B2: all half-0 reads done
    #pragma unroll
    for (int mm = 32; mm < 64; ++mm) step(mm);    // half 1 (red streamed)
    __syncthreads();               // B3: half-1 partials visible
    softmax_store(1);
}

extern "C" void kernel_launch(void* const* d_in, const int* in_sizes, int n_in,
                              void* d_out, int out_size, void* d_ws, size_t ws_size,
                              hipStream_t stream) {
    const int*   x    = (const int*)d_in[0];
    const float* W    = (const float*)d_in[1];
    const float* c    = (const float*)d_in[2];
    const float* V    = (const float*)d_in[3];
    const float* bias = (const float*)d_in[4];
    float* out = (float*)d_out;

    char* ws = (char*)d_ws;
    size_t off = 0;
    _Float16* Wt2h = (_Float16*)(ws + off);
    off += (size_t)D_DIM * H_DIM * sizeof(_Float16);
    off = (off + 255) & ~(size_t)255;
    _Float16* VB = (_Float16*)(ws + off);
    off += (size_t)D_DIM * 32 * 64 * 8 * sizeof(_Float16);
    off = (off + 255) & ~(size_t)255;
    _Float16* PA = (_Float16*)(ws + off);

    k_prep2<<<dim3(PSCAN_BLKS + VPREP_BLKS + WPREP_BLKS), 256, 0, stream>>>(W, V, c, x, Wt2h, VB, PA);
    k_main<<<dim3(B_DIM / BT, T_CH), 256, 0, stream>>>(VB, Wt2h, PA, x, bias, out);
}